// Round 8
// baseline (1891.179 us; speedup 1.0000x reference)
//
#include <hip/hip_runtime.h>

typedef __bf16 bf16_t;
typedef __attribute__((ext_vector_type(8))) __bf16 bf16x8;
typedef __attribute__((ext_vector_type(4))) __bf16 bf16x4;
typedef __attribute__((ext_vector_type(4))) float f32x4;

#define DEVINL __device__ __forceinline__

DEVINL void gload16(const void* g, void* l) {
  __builtin_amdgcn_global_load_lds(
      (const __attribute__((address_space(1))) void*)g,
      (__attribute__((address_space(3))) void*)l, 16, 0, 0);
}

// ---------------------------------------------------------------------------
// gemm256r: deep-grid GEMMs (qkv, fc1). 256x256 tile, BK=32, 512 thr
// (8 waves 2Mx4N), 2-slot LDS ring (64 KiB -> 2 blocks/CU), one barrier
// per K-tile; full-drain vmcnt(0) per tile is covered by the co-resident
// block (m114 inter-block overlap).
// ---------------------------------------------------------------------------
template <int OUT>
__global__ __launch_bounds__(512) void gemm256r(
    const bf16_t* __restrict__ A, const bf16_t* __restrict__ Bt,
    void* __restrict__ Cv, int M, int N, int K,
    const float* __restrict__ bias, const float* __restrict__ resid,
    const float* __restrict__ gate, int GM)
{
  __shared__ __align__(16) bf16_t sL[2][2][256 * 32];
  const int tid = threadIdx.x;
  const int lane = tid & 63;
  const int wave = tid >> 6;
  const int wr = wave >> 2;
  const int wc = wave & 3;

  const int nbx = gridDim.x, nby = gridDim.y;
  const int nwg = nbx * nby;
  int lin = (int)blockIdx.y * nbx + (int)blockIdx.x;
  {
    const int q = nwg >> 3, rr = nwg & 7;
    const int xcd = lin & 7, idx = lin >> 3;
    lin = (xcd < rr ? xcd * (q + 1) : rr * (q + 1) + (xcd - rr) * q) + idx;
  }
  const int per_grp = GM * nbx;
  const int gid = lin / per_grp;
  const int rem = lin - gid * per_grp;
  const int gsz = min(GM, nby - gid * GM);
  const long tileM = (long)(gid * GM + rem % gsz) * 256;
  const long tileN = (long)(rem / gsz) * 256;

  const int r0 = tid >> 2;
  const int c0 = (((tid & 3) - (r0 >> 2)) & 3) * 8;

  auto STAGE = [&](int slot, int kt) {
    const bf16_t* ga = A + (tileM + r0) * (long)K + kt + c0;
    const bf16_t* gb = Bt + (tileN + r0) * (long)K + kt + c0;
    char* la = (char*)&sL[slot][0][0] + tid * 16;
    char* lb = (char*)&sL[slot][1][0] + tid * 16;
    gload16(ga, la);
    gload16(ga + 128 * (long)K, la + 8192);
    gload16(gb, lb);
    gload16(gb + 128 * (long)K, lb + 8192);
  };

  f32x4 acc[8][4] = {};
  const int NT = K >> 5;

  STAGE(0, 0); STAGE(1, 32);
  asm volatile("s_waitcnt vmcnt(4)" ::: "memory");   // tile 0 landed
  asm volatile("s_barrier" ::: "memory");

  const int r = lane & 15;
  const int kg = lane >> 4;
  const int sw = ((kg + (r >> 2)) & 3) * 16;
  const int abyte = (wr * 128 + r) * 64 + sw;
  const int bbyte = (wc * 64 + r) * 64 + sw;

  for (int t = 0; t < NT; ++t) {
    const char* pA = (const char*)&sL[t & 1][0][0];
    const char* pB = (const char*)&sL[t & 1][1][0];
    bf16x8 a[8], b[4];
#pragma unroll
    for (int n = 0; n < 4; ++n) b[n] = *(const bf16x8*)(pB + bbyte + n * 1024);
#pragma unroll
    for (int m = 0; m < 8; ++m) a[m] = *(const bf16x8*)(pA + abyte + m * 1024);
    __builtin_amdgcn_s_setprio(1);
#pragma unroll
    for (int m = 0; m < 8; ++m)
#pragma unroll
      for (int n = 0; n < 4; ++n)
        acc[m][n] = __builtin_amdgcn_mfma_f32_16x16x32_bf16(a[m], b[n],
                                                            acc[m][n], 0, 0, 0);
    __builtin_amdgcn_s_setprio(0);
    if (t + 1 >= NT) break;
    asm volatile("s_waitcnt vmcnt(0)" ::: "memory"); // tile t+1 landed
    asm volatile("s_barrier" ::: "memory");          // all waves done w/ slot t
    if (t + 2 < NT) STAGE(t & 1, (t + 2) << 5);      // refill freed slot
  }

  const long row0 = tileM + wr * 128 + ((lane >> 4) * 4);
  const int col0 = (int)tileN + wc * 64 + r;
#pragma unroll
  for (int m = 0; m < 8; ++m) {
#pragma unroll
    for (int n = 0; n < 4; ++n) {
      const int col = col0 + n * 16;
      if (col < N) {
        const float bb = bias ? bias[col] : 0.0f;
#pragma unroll
        for (int j = 0; j < 4; ++j) {
          const long row = row0 + m * 16 + j;
          const long idx = row * (long)N + col;
          const float v = acc[m][n][j] + bb;
          if constexpr (OUT == 1) {
            const float g = gate ? gate[(row >> 12) * 6912 + col] : 1.0f;
            const float rv = resid ? resid[idx] : 0.0f;
            ((float*)Cv)[idx] = rv + g * v;
          } else {
            ((bf16_t*)Cv)[idx] = (bf16_t)v;
          }
        }
      }
    }
  }
}

// ---------------------------------------------------------------------------
// gemm_bt (m97 128x128, ~3 blocks/CU): N=1152 GEMMs + cond/CA.
// OUT=0: C bf16 (+bias), batched. OUT=1: f32 resid+gate. OUT=2: PV scatter.
// OUT=3: fused q-repack: qcp[((b*16+h)*4096+n)*96+d] = (acc+bias)*72^-0.5
// ---------------------------------------------------------------------------
template <int OUT>
__global__ __launch_bounds__(256) void gemm_bt(
    const bf16_t* __restrict__ A, const bf16_t* __restrict__ Bt,
    void* __restrict__ Cv, int M, int N, int K,
    long strideA, long strideB, long strideC,
    const float* __restrict__ bias, const float* __restrict__ resid,
    const float* __restrict__ gate, int GM)
{
  __shared__ __align__(16) bf16_t sA[128 * 32];
  __shared__ __align__(16) bf16_t sB[128 * 32];
  const int tid = threadIdx.x;
  const int lane = tid & 63;
  const int wave = tid >> 6;
  const bf16_t* Ab = A + (size_t)blockIdx.z * strideA;
  const bf16_t* Bb = Bt + (size_t)blockIdx.z * strideB;

  const int nbx = gridDim.x, nby = gridDim.y;
  const int nwg = nbx * nby;
  int lin = (int)blockIdx.y * nbx + (int)blockIdx.x;
  {
    const int q = nwg >> 3, rr = nwg & 7;
    const int xcd = lin & 7, idx = lin >> 3;
    lin = (xcd < rr ? xcd * (q + 1) : rr * (q + 1) + (xcd - rr) * q) + idx;
  }
  const int per_grp = GM * nbx;
  const int gid = lin / per_grp;
  const int rem = lin - gid * per_grp;
  const int gsz = min(GM, nby - gid * GM);
  const long tileM = (long)(gid * GM + rem % gsz) * 128;
  const long tileN = (long)(rem / gsz) * 128;
  const int wr = wave >> 1, wc = wave & 1;

  f32x4 acc[4][4] = {};

  const int srow = lane >> 2;
  const int skcol = (lane & 3) * 8;
  const bf16_t* gA0 = Ab + (tileM + wave * 16 + srow) * (long)K + skcol;
  const bf16_t* gB0 = Bb + (tileN + wave * 16 + srow) * (long)K + skcol;
  bf16_t* lA0 = sA + wave * 512;
  bf16_t* lB0 = sB + wave * 512;
  const long rs64 = 64L * K;

  const int aoff = (wr * 64 + (lane & 15)) * 32 + (lane >> 4) * 8;
  const int boff = (wc * 64 + (lane & 15)) * 32 + (lane >> 4) * 8;

  for (int kt = 0; kt < K; kt += 32) {
    __syncthreads();
    gload16(gA0 + kt, lA0);
    gload16(gA0 + kt + rs64, lA0 + 2048);
    gload16(gB0 + kt, lB0);
    gload16(gB0 + kt + rs64, lB0 + 2048);
    __syncthreads();
    bf16x8 av[4], bv[4];
#pragma unroll
    for (int m = 0; m < 4; ++m) av[m] = *(const bf16x8*)&sA[aoff + m * 512];
#pragma unroll
    for (int n = 0; n < 4; ++n) bv[n] = *(const bf16x8*)&sB[boff + n * 512];
#pragma unroll
    for (int m = 0; m < 4; ++m)
#pragma unroll
      for (int n = 0; n < 4; ++n)
        acc[m][n] = __builtin_amdgcn_mfma_f32_16x16x32_bf16(av[m], bv[n],
                                                            acc[m][n], 0, 0, 0);
  }

  const long row0 = tileM + wr * 64 + ((lane >> 4) * 4);
  const int col0 = (int)tileN + wc * 64 + (lane & 15);
#pragma unroll
  for (int m = 0; m < 4; ++m) {
#pragma unroll
    for (int n = 0; n < 4; ++n) {
      const int col = col0 + n * 16;
      const float bb = (OUT != 2 && bias) ? bias[col] : 0.0f;
#pragma unroll
      for (int j = 0; j < 4; ++j) {
        const long row = row0 + m * 16 + j;
        const float v = acc[m][n][j] + bb;
        if constexpr (OUT == 1) {
          const long idx = row * (long)N + col;
          const float g = gate ? gate[(row >> 12) * 6912 + col] : 1.0f;
          const float rv = resid ? resid[idx] : 0.0f;
          ((float*)Cv)[idx] = rv + g * v;
        } else if constexpr (OUT == 2) {
          if (col < 72)
            ((bf16_t*)Cv)[(((long)(blockIdx.z >> 4)) * 4096 + row) * 1152 +
                          (long)(blockIdx.z & 15) * 72 + col] = (bf16_t)v;
        } else if constexpr (OUT == 3) {
          const int h = col / 72, d = col - h * 72;
          const long b = row >> 12, n4 = row & 4095;
          ((bf16_t*)Cv)[((b * 16 + h) * 4096 + n4) * 96 + d] =
              (bf16_t)(v * 0.11785113019775793f);
        } else {
          const long idx = row * (long)N + col;
          (((bf16_t*)Cv) + (size_t)blockIdx.z * strideC)[idx] = (bf16_t)v;
        }
      }
    }
  }
}

// ---------------------------------------------------------------------------
__global__ __launch_bounds__(256) void transpose_cast(
    const float* __restrict__ W, bf16_t* __restrict__ WT, int K, int N)
{
  __shared__ float tile[32][33];
  const int n0 = blockIdx.x * 32, k0 = blockIdx.y * 32;
  const int tx = threadIdx.x & 31, ty = threadIdx.x >> 5;
#pragma unroll
  for (int r = ty; r < 32; r += 8) tile[r][tx] = W[(size_t)(k0 + r) * N + n0 + tx];
  __syncthreads();
#pragma unroll
  for (int r = ty; r < 32; r += 8)
    WT[(size_t)(n0 + r) * K + k0 + tx] = (bf16_t)tile[tx][r];
}

__global__ __launch_bounds__(256) void ada_kernel(
    const float* __restrict__ t_emb, const float* __restrict__ w_ada,
    const float* __restrict__ b_ada, const float* __restrict__ sst,
    float* __restrict__ ada)
{
  __shared__ float st[4][1152];
  const int t = threadIdx.x;
  const int j = blockIdx.x * 256 + t;
  for (int i = t; i < 4 * 1152; i += 256) {
    const int b = i / 1152, cc = i % 1152;
    const float v = t_emb[b * 1152 + cc];
    st[b][cc] = v / (1.0f + __expf(-v));
  }
  __syncthreads();
  const int k0 = blockIdx.y * 144;
  float a0 = 0.f, a1 = 0.f, a2 = 0.f, a3 = 0.f;
  for (int k = k0; k < k0 + 144; ++k) {
    const float w = w_ada[(size_t)k * 6912 + j];
    a0 += st[0][k] * w; a1 += st[1][k] * w;
    a2 += st[2][k] * w; a3 += st[3][k] * w;
  }
  if (blockIdx.y == 0) {
    const float base = b_ada[j] + sst[j];
    a0 += base; a1 += base; a2 += base; a3 += base;
  }
  atomicAdd(&ada[0 * 6912 + j], a0);
  atomicAdd(&ada[1 * 6912 + j], a1);
  atomicAdd(&ada[2 * 6912 + j], a2);
  atomicAdd(&ada[3 * 6912 + j], a3);
}

__global__ __launch_bounds__(256) void ln_mod(
    const float* __restrict__ X, bf16_t* __restrict__ out,
    const float* __restrict__ adaB, int shiftIdx, int scaleIdx,
    const float* __restrict__ gamma, const float* __restrict__ beta)
{
  const int row = blockIdx.x;
  const float4* xr4 = (const float4*)(X + (size_t)row * 1152);
  float s = 0.f, s2 = 0.f;
  for (int i = threadIdx.x; i < 288; i += 256) {
    const float4 v = xr4[i];
    s += v.x + v.y + v.z + v.w;
    s2 += v.x * v.x + v.y * v.y + v.z * v.z + v.w * v.w;
  }
  const int lane = threadIdx.x & 63, wave = threadIdx.x >> 6;
#pragma unroll
  for (int o = 32; o; o >>= 1) { s += __shfl_down(s, o); s2 += __shfl_down(s2, o); }
  __shared__ float rs[4], rq[4];
  if (lane == 0) { rs[wave] = s; rq[wave] = s2; }
  __syncthreads();
  if (threadIdx.x == 0) {
    rs[0] = rs[0] + rs[1] + rs[2] + rs[3];
    rq[0] = rq[0] + rq[1] + rq[2] + rq[3];
  }
  __syncthreads();
  const float mu = rs[0] * (1.0f / 1152.0f);
  const float var = rq[0] * (1.0f / 1152.0f) - mu * mu;
  const float inv = rsqrtf(var + 1e-6f);
  const int b = row >> 12;
  const float4* shiftv = (const float4*)(adaB ? adaB + b * 6912 + shiftIdx * 1152 : beta);
  const float4* scalev = (const float4*)(adaB ? adaB + b * 6912 + scaleIdx * 1152 : gamma);
  const float add1 = adaB ? 1.0f : 0.0f;
  for (int i = threadIdx.x; i < 288; i += 256) {
    const float4 v = xr4[i];
    const float4 sc = scalev[i];
    const float4 sh = shiftv[i];
    bf16x4 o;
    o[0] = (bf16_t)((v.x - mu) * inv * (add1 + sc.x) + sh.x);
    o[1] = (bf16_t)((v.y - mu) * inv * (add1 + sc.y) + sh.y);
    o[2] = (bf16_t)((v.z - mu) * inv * (add1 + sc.z) + sh.z);
    o[3] = (bf16_t)((v.w - mu) * inv * (add1 + sc.w) + sh.w);
    *(bf16x4*)&out[(size_t)row * 1152 + i * 4] = o;
  }
}

__global__ void pad_cond_k(const float* __restrict__ cond, bf16_t* __restrict__ condp)
{
  const int idx = blockIdx.x * 256 + threadIdx.x;
  const int row = idx / 1152;
  condp[idx] = (row < 1200) ? (bf16_t)cond[idx] : (bf16_t)0.0f;
}

__global__ __launch_bounds__(256) void sa_kv_k(
    const bf16_t* __restrict__ qkv, float* __restrict__ kvb, float* __restrict__ ksumb)
{
  const int bh = blockIdx.x, b = bh / 36, h = bh % 36;
  __shared__ bf16_t sk[32][32], sv[32][32];
  const int t = threadIdx.x;
  const int nn = t >> 5, c = t & 31;
  const int srow = (t & 127) >> 2;
  const int sq4 = (t & 3) * 8;
  const int isV = t >> 7;
  float a0 = 0.f, a1 = 0.f, a2 = 0.f, a3 = 0.f, ks = 0.f;
  const size_t rowbase = (size_t)b * 4096 + (size_t)blockIdx.y * 256;
  const size_t colbase = 1152 + (size_t)isV * 1152 + h * 32 + sq4;
  for (int n0 = 0; n0 < 256; n0 += 32) {
    __syncthreads();
    const bf16x8 v8 = *(const bf16x8*)&qkv[(rowbase + n0 + srow) * 3456 + colbase];
    if (isV == 0) {
      bf16x8 r8;
#pragma unroll
      for (int j = 0; j < 8; ++j) r8[j] = (bf16_t)fmaxf((float)v8[j], 0.0f);
      *(bf16x8*)&sk[srow][sq4] = r8;
    } else {
      *(bf16x8*)&sv[srow][sq4] = v8;
    }
    __syncthreads();
#pragma unroll
    for (int q = 0; q < 32; ++q) {
      const float vv = (float)sv[q][c];
      a0 += (float)sk[q][nn] * vv;
      a1 += (float)sk[q][nn + 8] * vv;
      a2 += (float)sk[q][nn + 16] * vv;
      a3 += (float)sk[q][nn + 24] * vv;
    }
    if (t < 32) {
#pragma unroll
      for (int q = 0; q < 32; ++q) ks += (float)sk[q][t];
    }
  }
  float* kvp = kvb + (size_t)bh * 1024;
  atomicAdd(&kvp[(nn + 0) * 32 + c], a0);
  atomicAdd(&kvp[(nn + 8) * 32 + c], a1);
  atomicAdd(&kvp[(nn + 16) * 32 + c], a2);
  atomicAdd(&kvp[(nn + 24) * 32 + c], a3);
  if (t < 32) atomicAdd(&ksumb[bh * 32 + t], ks);
}

__global__ __launch_bounds__(256) void sa_out_k(
    const bf16_t* __restrict__ qkv, const float* __restrict__ kvb,
    const float* __restrict__ ksumb, bf16_t* __restrict__ so)
{
  const int row0 = blockIdx.x * 8;
  const int b = row0 >> 12;
  __shared__ float q[8][1152];
  __shared__ float denom[8][36];
  const int t = threadIdx.x;
  for (int i = t; i < 1152; i += 256) {
    const int r = i / 144, c0 = (i % 144) * 8;
    const bf16x8 v8 = *(const bf16x8*)&qkv[(size_t)(row0 + r) * 3456 + c0];
#pragma unroll
    for (int j = 0; j < 8; ++j) q[r][c0 + j] = fmaxf((float)v8[j], 0.0f);
  }
  __syncthreads();
  for (int i = t; i < 288; i += 256) {
    int r = i / 36, h = i % 36;
    const float* ksp = ksumb + (b * 36 + h) * 32;
    float dsum = 1e-6f;
#pragma unroll
    for (int d = 0; d < 32; ++d) dsum += q[r][h * 32 + d] * ksp[d];
    denom[r][h] = dsum;
  }
  __syncthreads();
  for (int j = t; j < 1152; j += 256) {
    const int h = j >> 5, e = j & 31;
    const float* kvp = kvb + ((size_t)(b * 36 + h)) * 1024 + e;
    float kreg[32];
#pragma unroll
    for (int d = 0; d < 32; ++d) kreg[d] = kvp[d * 32];
#pragma unroll
    for (int r = 0; r < 8; ++r) {
      float a = 0.f;
#pragma unroll
      for (int d = 0; d < 32; ++d) a += q[r][h * 32 + d] * kreg[d];
      so[(size_t)(row0 + r) * 1152 + j] = (bf16_t)(a / denom[r][h]);
    }
  }
}

__global__ void ca_qrepack(const bf16_t* __restrict__ qc, bf16_t* __restrict__ qcp, int b)
{
  const size_t idx = (size_t)blockIdx.x * 256 + threadIdx.x;
  const int d = (int)(idx % 96);
  const size_t r = idx / 96;
  const int n = (int)(r & 4095);
  const int h = (int)(r >> 12);
  float v = 0.f;
  if (d < 72) v = (float)qc[((size_t)(b * 4096 + n)) * 1152 + h * 72 + d] * 0.11785113019775793f;
  qcp[idx] = (bf16_t)v;
}

__global__ void ca_kcrepack(const bf16_t* __restrict__ kvc, bf16_t* __restrict__ kcp, int b)
{
  const size_t idx = (size_t)blockIdx.x * 256 + threadIdx.x;
  const int d = (int)(idx % 96);
  const size_t r = idx / 96;
  const int m = (int)(r % 384);
  const int h = (int)(r / 384);
  bf16_t v = (bf16_t)0.0f;
  if (d < 72 && m < 300) v = kvc[((size_t)(b * 300 + m)) * 2304 + h * 72 + d];
  kcp[idx] = v;
}

__global__ void ca_vtrepack(const bf16_t* __restrict__ kvc, bf16_t* __restrict__ vt, int b)
{
  const size_t idx = (size_t)blockIdx.x * 256 + threadIdx.x;
  const int m = (int)(idx % 384);
  const size_t r = idx / 384;
  const int d = (int)(r & 127);
  const int h = (int)(r >> 7);
  bf16_t v = (bf16_t)0.0f;
  if (d < 72 && m < 300) v = kvc[((size_t)(b * 300 + m)) * 2304 + 1152 + h * 72 + d];
  vt[idx] = v;
}

__global__ __launch_bounds__(256) void softmax_k(bf16_t* __restrict__ s)
{
  const int row = blockIdx.x * 4 + (threadIdx.x >> 6);
  const int lane = threadIdx.x & 63;
  bf16_t* sr = s + (size_t)row * 384;
  float v[5];
  float mx = -1e30f;
#pragma unroll
  for (int i = 0; i < 5; ++i) {
    const int m = lane + 64 * i;
    v[i] = (m < 300) ? (float)sr[m] : -1e30f;
    mx = fmaxf(mx, v[i]);
  }
#pragma unroll
  for (int o = 32; o; o >>= 1) mx = fmaxf(mx, __shfl_xor(mx, o));
  float sum = 0.f;
#pragma unroll
  for (int i = 0; i < 5; ++i) { v[i] = __expf(v[i] - mx); sum += v[i]; }
#pragma unroll
  for (int o = 32; o; o >>= 1) sum += __shfl_xor(sum, o);
  const float inv = 1.0f / sum;
#pragma unroll
  for (int i = 0; i < 5; ++i) {
    const int m = lane + 64 * i;
    if (m < 320) sr[m] = (bf16_t)(v[i] * inv);
  }
}

__global__ void glu_k(const bf16_t* __restrict__ gv, bf16_t* __restrict__ h)
{
  const size_t idx = (size_t)blockIdx.x * 256 + threadIdx.x;
  const size_t row = idx / 360;
  const int c0 = (int)(idx % 360) * 8;
  const bf16x8 g8 = *(const bf16x8*)&gv[row * 5760 + c0];
  const bf16x8 v8 = *(const bf16x8*)&gv[row * 5760 + 2880 + c0];
  bf16x8 o;
#pragma unroll
  for (int j = 0; j < 8; ++j) {
    const float g = (float)g8[j];
    const float sg = g / (1.0f + __expf(-g));
    o[j] = (bf16_t)(sg * (float)v8[j]);
  }
  *(bf16x8*)&h[row * 2880 + c0] = o;
}

__global__ __launch_bounds__(256) void dwconv_k(
    const bf16_t* __restrict__ h, const float* __restrict__ wk,
    const float* __restrict__ wb, bf16_t* __restrict__ hc)
{
  const size_t idx = (size_t)blockIdx.x * 256 + threadIdx.x;
  const int c8 = (int)(idx % 360);
  size_t p = idx / 360;
  const int x = (int)(p & 63);
  const int y = (int)(p >> 6);
  const int c0 = c8 * 8;
  float acc[8];
#pragma unroll
  for (int j = 0; j < 8; ++j) acc[j] = wb[c0 + j];
  for (int ky = -1; ky <= 1; ++ky) {
    const int yy = y + ky;
    if (yy < 0 || yy > 63) continue;
    for (int kx = -1; kx <= 1; ++kx) {
      const int xx = x + kx;
      if (xx < 0 || xx > 63) continue;
      const bf16x8 v = *(const bf16x8*)&h[((size_t)(yy * 64 + xx)) * 2880 + c0];
      const float* w = wk + ((ky + 1) * 3 + (kx + 1)) * 2880 + c0;
#pragma unroll
      for (int j = 0; j < 8; ++j) acc[j] += (float)v[j] * w[j];
    }
  }
  bf16x8 o;
#pragma unroll
  for (int j = 0; j < 8; ++j) o[j] = (bf16_t)acc[j];
  *(bf16x8*)&hc[((size_t)(y * 64 + x)) * 2880 + c0] = o;
}

// ---------------------------------------------------------------------------
extern "C" void kernel_launch(void* const* d_in, const int* in_sizes, int n_in,
                              void* d_out, int out_size, void* d_ws, size_t ws_size,
                              hipStream_t stream)
{
  const float* x          = (const float*)d_in[0];
  const float* cond       = (const float*)d_in[1];
  const float* t_emb      = (const float*)d_in[2];
  const float* w_qkv      = (const float*)d_in[3];
  const float* w_sa_out   = (const float*)d_in[4];
  const float* b_sa_out   = (const float*)d_in[5];
  const float* gamma_cr   = (const float*)d_in[6];
  const float* beta_cr    = (const float*)d_in[7];
  const float* w_q        = (const float*)d_in[8];
  const float* b_q        = (const float*)d_in[9];
  const float* w_kv       = (const float*)d_in[10];
  const float* b_kv       = (const float*)d_in[11];
  const float* w_co       = (const float*)d_in[12];
  const float* b_co       = (const float*)d_in[13];
  const float* w_fc1      = (const float*)d_in[14];
  const float* b_fc1      = (const float*)d_in[15];
  const float* dw_kernel  = (const float*)d_in[16];
  const float* dw_bias    = (const float*)d_in[17];
  const float* w_fc2      = (const float*)d_in[18];
  const float* b_fc2      = (const float*)d_in[19];
  const float* w_ada      = (const float*)d_in[20];
  const float* b_ada      = (const float*)d_in[21];
  const float* sst        = (const float*)d_in[22];
  float* out = (float*)d_out;  // f32 residual stream

  char* ws = (char*)d_ws;
  size_t off = 0;
  auto alloc = [&](size_t bytes) -> char* {
    off = (off + 255) & ~(size_t)255;
    char* p = ws + off;
    off += bytes;
    return p;
  };

  bf16_t* wqkvT  = (bf16_t*)alloc((size_t)3584 * 1152 * 2);
  bf16_t* wsaT   = (bf16_t*)alloc((size_t)1280 * 1152 * 2);
  bf16_t* wqT    = (bf16_t*)alloc((size_t)1280 * 1152 * 2);
  bf16_t* wkvT   = (bf16_t*)alloc((size_t)2304 * 1152 * 2);
  bf16_t* wcoT   = (bf16_t*)alloc((size_t)1280 * 1152 * 2);
  bf16_t* wfc1T  = (bf16_t*)alloc((size_t)5888 * 1152 * 2);
  bf16_t* wfc2T  = (bf16_t*)alloc((size_t)1280 * 2880 * 2);
  float*  adaB   = (float*)alloc((size_t)4 * 6912 * 4);
  bf16_t* xn     = (bf16_t*)alloc((size_t)16384 * 1152 * 2);
  bf16_t* buf37  = (bf16_t*)alloc((size_t)16384 * 1152 * 2);
  float*  kvb    = (float*)alloc((size_t)144 * 1024 * 4);
  float*  ksumb  = (float*)alloc((size_t)144 * 32 * 4);
  bf16_t* condp  = (bf16_t*)alloc((size_t)1280 * 1152 * 2);
  bf16_t* kvcB   = (bf16_t*)alloc((size_t)1280 * 2304 * 2);

  const size_t ARENA_SMALL = (size_t)16384 * 3456 * 2;
  const size_t CA_Q = (size_t)64 * 4096 * 96 * 2;
  const size_t CA_K = (size_t)64 * 384 * 96 * 2;
  const size_t CA_V = (size_t)64 * 128 * 384 * 2;
  const size_t CA_S = (size_t)64 * 4096 * 384 * 2;
  const size_t ARENA_BIG = CA_Q + CA_K + CA_V + CA_S;
  const bool big = (off + 512 + ARENA_BIG) <= ws_size;
  char* arena = alloc(big ? ARENA_BIG : ARENA_SMALL);
  if (off > ws_size) return;

  bf16_t* qkvB = (bf16_t*)arena;
  bf16_t *qcp, *kcp, *vcT, *scores;
  if (big) {
    qcp    = (bf16_t*)arena;
    kcp    = (bf16_t*)(arena + CA_Q);
    vcT    = (bf16_t*)(arena + CA_Q + CA_K);
    scores = (bf16_t*)(arena + CA_Q + CA_K + CA_V);
  } else {
    qcp    = (bf16_t*)arena;
    kcp    = (bf16_t*)(arena + 12582912);
    vcT    = (bf16_t*)(arena + 12582912 + 1179648);
    scores = (bf16_t*)(arena + 12582912 + 1179648 + 1572864);
  }
  bf16_t *gvB, *hB, *hcB;
  if (big) {   // gv(2b) 94.4 | h(2b) 47.2 | hc(4b) 94.4  = 236 MB <= 262
    gvB = (bf16_t*)arena;
    hB  = (bf16_t*)(arena + (size_t)8192 * 5760 * 2);
    hcB = (bf16_t*)(arena + (size_t)8192 * 5760 * 2 + (size_t)8192 * 2880 * 2);
  } else {
    hcB = (bf16_t*)arena;
    gvB = (bf16_t*)(arena + (size_t)8192 * 2880 * 2);
    hB  = buf37;
  }

  hipMemsetAsync(adaB, 0, (size_t)4 * 6912 * 4, stream);
  hipMemsetAsync(kvb, 0, (size_t)144 * 1024 * 4, stream);
  hipMemsetAsync(ksumb, 0, (size_t)144 * 32 * 4, stream);

  // --- weight prep ---
  transpose_cast<<<dim3(108, 36), 256, 0, stream>>>(w_qkv, wqkvT, 1152, 3456);
  transpose_cast<<<dim3(36, 36), 256, 0, stream>>>(w_sa_out, wsaT, 1152, 1152);
  transpose_cast<<<dim3(36, 36), 256, 0, stream>>>(w_q, wqT, 1152, 1152);
  transpose_cast<<<dim3(72, 36), 256, 0, stream>>>(w_kv, wkvT, 1152, 2304);
  transpose_cast<<<dim3(36, 36), 256, 0, stream>>>(w_co, wcoT, 1152, 1152);
  transpose_cast<<<dim3(180, 36), 256, 0, stream>>>(w_fc1, wfc1T, 1152, 5760);
  transpose_cast<<<dim3(36, 90), 256, 0, stream>>>(w_fc2, wfc2T, 2880, 1152);
  ada_kernel<<<dim3(27, 8), 256, 0, stream>>>(t_emb, w_ada, b_ada, sst, adaB);
  pad_cond_k<<<5760, 256, 0, stream>>>(cond, condp);

  // --- self (linear) attention ---
  ln_mod<<<16384, 256, 0, stream>>>(x, xn, adaB, 0, 1, nullptr, nullptr);
  gemm256r<0><<<dim3(14, 64), 512, 0, stream>>>(xn, wqkvT, qkvB, 16384, 3456, 1152,
                                                nullptr, nullptr, nullptr, 8);
  sa_kv_k<<<dim3(144, 16), 256, 0, stream>>>(qkvB, kvb, ksumb);
  sa_out_k<<<2048, 256, 0, stream>>>(qkvB, kvb, ksumb, buf37);
  gemm_bt<1><<<dim3(9, 128), 256, 0, stream>>>(buf37, wsaT, out, 16384, 1152, 1152,
                                               0, 0, 0, b_sa_out, x, adaB + 2 * 1152, 8);

  // --- cross attention ---
  ln_mod<<<16384, 256, 0, stream>>>(out, xn, nullptr, 0, 0, gamma_cr, beta_cr);
  gemm_bt<0><<<dim3(18, 10, 1), 256, 0, stream>>>(condp, wkvT, kvcB, 1280, 2304, 1152,
                                                  0, 0, 0, b_kv, nullptr, nullptr, 8);
  if (big) {
    hipMemsetAsync(qcp, 0, CA_Q, stream);          // zero d-padding (after SA)
    gemm_bt<3><<<dim3(9, 128), 256, 0, stream>>>(xn, wqT, qcp, 16384, 1152, 1152,
                                                 0, 0, 0, b_q, nullptr, nullptr, 8);
    for (int b = 0; b < 4; ++b) {
      ca_kcrepack<<<2304, 256, 0, stream>>>(kvcB, kcp + (size_t)b * 16 * 384 * 96, b);
      ca_vtrepack<<<3072, 256, 0, stream>>>(kvcB, vcT + (size_t)b * 16 * 128 * 384, b);
    }
    gemm_bt<0><<<dim3(3, 32, 64), 256, 0, stream>>>(qcp, kcp, scores, 4096, 384, 96,
                                                    (long)4096 * 96, (long)384 * 96,
                                                    (long)4096 * 384, nullptr, nullptr, nullptr, 8);
    softmax_k<<<65536, 256, 0, stream>>>(scores);
    gemm_bt<2><<<dim3(1, 32, 64), 256, 0, stream>>>(scores, vcT, buf37, 4096, 128, 384,
                                                    (long)4096 * 384, (long)128 * 384,
                                                    0, nullptr, nullptr, nullptr, 8);
  } else {
    gemm_bt<0><<<dim3(9, 128), 256, 0, stream>>>(xn, wqT, buf37, 16384, 1152, 1152,
                                                 0, 0, 0, b_q, nullptr, nullptr, 8);
    for (int b = 0; b < 4; ++b) {
      ca_qrepack<<<24576, 256, 0, stream>>>(buf37, qcp, b);
      ca_kcrepack<<<2304, 256, 0, stream>>>(kvcB, kcp, b);
      ca_vtrepack<<<3072, 256, 0, stream>>>(kvcB, vcT, b);
      gemm_bt<0><<<dim3(3, 32, 16), 256, 0, stream>>>(qcp, kcp, scores, 4096, 384, 96,
                                                      (long)4096 * 96, (long)384 * 96,
                                                      (long)4096 * 384, nullptr, nullptr, nullptr, 8);
      softmax_k<<<16384, 256, 0, stream>>>(scores);
      gemm_bt<2><<<dim3(1, 32, 16), 256, 0, stream>>>(scores, vcT,
                                                      buf37 + (size_t)b * 4096 * 1152,
                                                      4096, 128, 384,
                                                      (long)4096 * 384, (long)128 * 384,
                                                      0, nullptr, nullptr, nullptr, 8);
    }
  }
  gemm_bt<1><<<dim3(9, 128), 256, 0, stream>>>(buf37, wcoT, out, 16384, 1152, 1152,
                                               0, 0, 0, b_co, out, nullptr, 8);

  // --- FF (GLU + depthwise conv) ---
  ln_mod<<<16384, 256, 0, stream>>>(out, xn, adaB, 3, 4, nullptr, nullptr);
  if (big) {
    for (int c = 0; c < 2; ++c) {
      gemm256r<0><<<dim3(23, 32), 512, 0, stream>>>(xn + (size_t)c * 8192 * 1152, wfc1T,
                                                    gvB, 8192, 5760, 1152,
                                                    b_fc1, nullptr, nullptr, 8);
      glu_k<<<11520, 256, 0, stream>>>(gvB, hB);
      for (int bb = 0; bb < 2; ++bb)
        dwconv_k<<<5760, 256, 0, stream>>>(hB + (size_t)bb * 4096 * 2880,
                                           dw_kernel, dw_bias,
                                           hcB + (size_t)(c * 2 + bb) * 4096 * 2880);
    }
    gemm_bt<1><<<dim3(9, 128), 256, 0, stream>>>(hcB, wfc2T, out, 16384, 1152, 2880,
                                                 0, 0, 0, b_fc2, out,
                                                 adaB + 5 * 1152, 8);
  } else {
    for (int c = 0; c < 2; ++c) {
      for (int bb = 0; bb < 2; ++bb) {
        const int b = c * 2 + bb;
        gemm256r<0><<<dim3(23, 16), 512, 0, stream>>>(xn + (size_t)b * 4096 * 1152, wfc1T,
                                                      gvB, 4096, 5760, 1152,
                                                      b_fc1, nullptr, nullptr, 8);
        glu_k<<<5760, 256, 0, stream>>>(gvB, hB);
        dwconv_k<<<5760, 256, 0, stream>>>(hB, dw_kernel, dw_bias,
                                           hcB + (size_t)bb * 4096 * 2880);
      }
      gemm_bt<1><<<dim3(9, 64), 256, 0, stream>>>(hcB, wfc2T,
                                                  out + (size_t)c * 8192 * 1152,
                                                  8192, 1152, 2880, 0, 0, 0, b_fc2,
                                                  out + (size_t)c * 8192 * 1152,
                                                  adaB + (size_t)c * 2 * 6912 + 5 * 1152, 8);
    }
  }

  (void)in_sizes; (void)n_in; (void)out_size; (void)ws_size;
}

// Round 9
// 1783.751 us; speedup vs baseline: 1.0602x; 1.0602x over previous
//
#include <hip/hip_runtime.h>

typedef __bf16 bf16_t;
typedef __attribute__((ext_vector_type(8))) __bf16 bf16x8;
typedef __attribute__((ext_vector_type(4))) __bf16 bf16x4;
typedef __attribute__((ext_vector_type(4))) float f32x4;

#define DEVINL __device__ __forceinline__

DEVINL void gload16(const void* g, void* l) {
  __builtin_amdgcn_global_load_lds(
      (const __attribute__((address_space(1))) void*)g,
      (__attribute__((address_space(3))) void*)l, 16, 0, 0);
}

// ---------------------------------------------------------------------------
// gemm256r: deep-grid GEMMs (qkv, fc1). 256x256 tile, BK=32, 512 thr
// (8 waves 2Mx4N), 3-slot LDS ring (96 KiB), one barrier per K-tile,
// stage 3 tiles ahead, counted vmcnt(4).  [R7-proven config]
// OUT=0: bf16 (+bias). OUT=1: f32 resid+gate.
// OUT=4: fused fc1+GLU: weights permuted in 32-blocks [gate16|val16];
//        h[row*2880 + hcol] = silu(g + b[hcol]) * (v + b[2880+hcol]).
// ---------------------------------------------------------------------------
template <int OUT>
__global__ __launch_bounds__(512) void gemm256r(
    const bf16_t* __restrict__ A, const bf16_t* __restrict__ Bt,
    void* __restrict__ Cv, int M, int N, int K,
    const float* __restrict__ bias, const float* __restrict__ resid,
    const float* __restrict__ gate, int GM)
{
  __shared__ __align__(16) bf16_t sL[3][2][256 * 32];
  const int tid = threadIdx.x;
  const int lane = tid & 63;
  const int wave = tid >> 6;
  const int wr = wave >> 2;
  const int wc = wave & 3;

  const int nbx = gridDim.x, nby = gridDim.y;
  const int nwg = nbx * nby;
  int lin = (int)blockIdx.y * nbx + (int)blockIdx.x;
  {
    const int q = nwg >> 3, rr = nwg & 7;
    const int xcd = lin & 7, idx = lin >> 3;
    lin = (xcd < rr ? xcd * (q + 1) : rr * (q + 1) + (xcd - rr) * q) + idx;
  }
  const int per_grp = GM * nbx;
  const int gid = lin / per_grp;
  const int rem = lin - gid * per_grp;
  const int gsz = min(GM, nby - gid * GM);
  const long tileM = (long)(gid * GM + rem % gsz) * 256;
  const long tileN = (long)(rem / gsz) * 256;

  const int r0 = tid >> 2;
  const int c0 = (((tid & 3) - (r0 >> 2)) & 3) * 8;

  auto STAGE = [&](int slot, int kt) {
    const bf16_t* ga = A + (tileM + r0) * (long)K + kt + c0;
    const bf16_t* gb = Bt + (tileN + r0) * (long)K + kt + c0;
    char* la = (char*)&sL[slot][0][0] + tid * 16;
    char* lb = (char*)&sL[slot][1][0] + tid * 16;
    gload16(ga, la);
    gload16(ga + 128 * (long)K, la + 8192);
    gload16(gb, lb);
    gload16(gb + 128 * (long)K, lb + 8192);
  };

  f32x4 acc[8][4] = {};
  const int NT = K >> 5;

  STAGE(0, 0); STAGE(1, 32); STAGE(2, 64);
  asm volatile("s_waitcnt vmcnt(8)" ::: "memory");   // tile 0 landed (this wave)
  asm volatile("s_barrier" ::: "memory");            // ...and all waves

  const int r = lane & 15;
  const int kg = lane >> 4;
  const int sw = ((kg + (r >> 2)) & 3) * 16;
  const int abyte = (wr * 128 + r) * 64 + sw;
  const int bbyte = (wc * 64 + r) * 64 + sw;

  int slot = 0;
  for (int t = 0; t < NT; ++t) {
    const char* pA = (const char*)&sL[slot][0][0];
    const char* pB = (const char*)&sL[slot][1][0];
    bf16x8 a[8], b[4];
#pragma unroll
    for (int n = 0; n < 4; ++n) b[n] = *(const bf16x8*)(pB + bbyte + n * 1024);
#pragma unroll
    for (int m = 0; m < 8; ++m) a[m] = *(const bf16x8*)(pA + abyte + m * 1024);
    __builtin_amdgcn_s_setprio(1);
#pragma unroll
    for (int m = 0; m < 8; ++m)
#pragma unroll
      for (int n = 0; n < 4; ++n)
        acc[m][n] = __builtin_amdgcn_mfma_f32_16x16x32_bf16(a[m], b[n],
                                                            acc[m][n], 0, 0, 0);
    __builtin_amdgcn_s_setprio(0);
    if (t + 1 >= NT) break;
    if (t + 2 < NT) asm volatile("s_waitcnt vmcnt(4)" ::: "memory");  // t+1 landed
    else            asm volatile("s_waitcnt vmcnt(0)" ::: "memory");
    asm volatile("s_barrier" ::: "memory");          // t+1 visible; slot t free
    if (t + 3 < NT) STAGE(slot, (t + 3) << 5);       // refill freed slot
    slot = (slot == 2) ? 0 : slot + 1;
  }

  const long row0 = tileM + wr * 128 + ((lane >> 4) * 4);
  const int col0 = (int)tileN + wc * 64 + r;
  if constexpr (OUT == 4) {
#pragma unroll
    for (int m = 0; m < 8; ++m) {
#pragma unroll
      for (int n = 0; n < 4; n += 2) {
        const int base = (int)tileN + wc * 64 + n * 16;   // multiple of 32
        if (base < 5760) {
          const int hcol = (base >> 1) + r;               // 16*(base/32) + r
          const float bg = bias[hcol];
          const float bv = bias[2880 + hcol];
#pragma unroll
          for (int j = 0; j < 4; ++j) {
            const long row = row0 + m * 16 + j;
            const float g = acc[m][n][j] + bg;
            const float v = acc[m][n + 1][j] + bv;
            const float sg = g / (1.0f + __expf(-g));
            ((bf16_t*)Cv)[row * 2880 + hcol] = (bf16_t)(sg * v);
          }
        }
      }
    }
    return;
  }
#pragma unroll
  for (int m = 0; m < 8; ++m) {
#pragma unroll
    for (int n = 0; n < 4; ++n) {
      const int col = col0 + n * 16;
      if (col < N) {
        const float bb = bias ? bias[col] : 0.0f;
#pragma unroll
        for (int j = 0; j < 4; ++j) {
          const long row = row0 + m * 16 + j;
          const long idx = row * (long)N + col;
          const float v = acc[m][n][j] + bb;
          if constexpr (OUT == 1) {
            const float g = gate ? gate[(row >> 12) * 6912 + col] : 1.0f;
            const float rv = resid ? resid[idx] : 0.0f;
            ((float*)Cv)[idx] = rv + g * v;
          } else {
            ((bf16_t*)Cv)[idx] = (bf16_t)v;
          }
        }
      }
    }
  }
}

// ---------------------------------------------------------------------------
// gemm_bt (m97 128x128, ~3 blocks/CU): N=1152 GEMMs + cond/CA.
// OUT=0: C bf16 (+bias), batched. OUT=1: f32 resid+gate. OUT=2: PV scatter.
// OUT=3: fused q-repack: qcp[((b*16+h)*4096+n)*96+d] = (acc+bias)*72^-0.5
// ---------------------------------------------------------------------------
template <int OUT>
__global__ __launch_bounds__(256) void gemm_bt(
    const bf16_t* __restrict__ A, const bf16_t* __restrict__ Bt,
    void* __restrict__ Cv, int M, int N, int K,
    long strideA, long strideB, long strideC,
    const float* __restrict__ bias, const float* __restrict__ resid,
    const float* __restrict__ gate, int GM)
{
  __shared__ __align__(16) bf16_t sA[128 * 32];
  __shared__ __align__(16) bf16_t sB[128 * 32];
  const int tid = threadIdx.x;
  const int lane = tid & 63;
  const int wave = tid >> 6;
  const bf16_t* Ab = A + (size_t)blockIdx.z * strideA;
  const bf16_t* Bb = Bt + (size_t)blockIdx.z * strideB;

  const int nbx = gridDim.x, nby = gridDim.y;
  const int nwg = nbx * nby;
  int lin = (int)blockIdx.y * nbx + (int)blockIdx.x;
  {
    const int q = nwg >> 3, rr = nwg & 7;
    const int xcd = lin & 7, idx = lin >> 3;
    lin = (xcd < rr ? xcd * (q + 1) : rr * (q + 1) + (xcd - rr) * q) + idx;
  }
  const int per_grp = GM * nbx;
  const int gid = lin / per_grp;
  const int rem = lin - gid * per_grp;
  const int gsz = min(GM, nby - gid * GM);
  const long tileM = (long)(gid * GM + rem % gsz) * 128;
  const long tileN = (long)(rem / gsz) * 128;
  const int wr = wave >> 1, wc = wave & 1;

  f32x4 acc[4][4] = {};

  const int srow = lane >> 2;
  const int skcol = (lane & 3) * 8;
  const bf16_t* gA0 = Ab + (tileM + wave * 16 + srow) * (long)K + skcol;
  const bf16_t* gB0 = Bb + (tileN + wave * 16 + srow) * (long)K + skcol;
  bf16_t* lA0 = sA + wave * 512;
  bf16_t* lB0 = sB + wave * 512;
  const long rs64 = 64L * K;

  const int aoff = (wr * 64 + (lane & 15)) * 32 + (lane >> 4) * 8;
  const int boff = (wc * 64 + (lane & 15)) * 32 + (lane >> 4) * 8;

  for (int kt = 0; kt < K; kt += 32) {
    __syncthreads();
    gload16(gA0 + kt, lA0);
    gload16(gA0 + kt + rs64, lA0 + 2048);
    gload16(gB0 + kt, lB0);
    gload16(gB0 + kt + rs64, lB0 + 2048);
    __syncthreads();
    bf16x8 av[4], bv[4];
#pragma unroll
    for (int m = 0; m < 4; ++m) av[m] = *(const bf16x8*)&sA[aoff + m * 512];
#pragma unroll
    for (int n = 0; n < 4; ++n) bv[n] = *(const bf16x8*)&sB[boff + n * 512];
#pragma unroll
    for (int m = 0; m < 4; ++m)
#pragma unroll
      for (int n = 0; n < 4; ++n)
        acc[m][n] = __builtin_amdgcn_mfma_f32_16x16x32_bf16(av[m], bv[n],
                                                            acc[m][n], 0, 0, 0);
  }

  const long row0 = tileM + wr * 64 + ((lane >> 4) * 4);
  const int col0 = (int)tileN + wc * 64 + (lane & 15);
#pragma unroll
  for (int m = 0; m < 4; ++m) {
#pragma unroll
    for (int n = 0; n < 4; ++n) {
      const int col = col0 + n * 16;
      const float bb = (OUT != 2 && bias) ? bias[col] : 0.0f;
#pragma unroll
      for (int j = 0; j < 4; ++j) {
        const long row = row0 + m * 16 + j;
        const float v = acc[m][n][j] + bb;
        if constexpr (OUT == 1) {
          const long idx = row * (long)N + col;
          const float g = gate ? gate[(row >> 12) * 6912 + col] : 1.0f;
          const float rv = resid ? resid[idx] : 0.0f;
          ((float*)Cv)[idx] = rv + g * v;
        } else if constexpr (OUT == 2) {
          if (col < 72)
            ((bf16_t*)Cv)[(((long)(blockIdx.z >> 4)) * 4096 + row) * 1152 +
                          (long)(blockIdx.z & 15) * 72 + col] = (bf16_t)v;
        } else if constexpr (OUT == 3) {
          const int h = col / 72, d = col - h * 72;
          const long b = row >> 12, n4 = row & 4095;
          ((bf16_t*)Cv)[((b * 16 + h) * 4096 + n4) * 96 + d] =
              (bf16_t)(v * 0.11785113019775793f);
        } else {
          const long idx = row * (long)N + col;
          (((bf16_t*)Cv) + (size_t)blockIdx.z * strideC)[idx] = (bf16_t)v;
        }
      }
    }
  }
}

// ---------------------------------------------------------------------------
__global__ __launch_bounds__(256) void transpose_cast(
    const float* __restrict__ W, bf16_t* __restrict__ WT, int K, int N)
{
  __shared__ float tile[32][33];
  const int n0 = blockIdx.x * 32, k0 = blockIdx.y * 32;
  const int tx = threadIdx.x & 31, ty = threadIdx.x >> 5;
#pragma unroll
  for (int r = ty; r < 32; r += 8) tile[r][tx] = W[(size_t)(k0 + r) * N + n0 + tx];
  __syncthreads();
#pragma unroll
  for (int r = ty; r < 32; r += 8)
    WT[(size_t)(n0 + r) * K + k0 + tx] = (bf16_t)tile[tx][r];
}

// fc1 weight permute+transpose: dst row n' = 32b+o reads W col (o<16 ? 16b+o
// : 2880+16b+o-16); pad rows (b>=180) zeroed. W is (1152, 5760) f32.
__global__ __launch_bounds__(256) void transpose_glu(
    const float* __restrict__ W, bf16_t* __restrict__ WT)
{
  __shared__ float tile[32][33];
  const int b = blockIdx.x;            // 0..183
  const int k0 = blockIdx.y * 32;
  const int tx = threadIdx.x & 31, ty = threadIdx.x >> 5;
  if (b < 180) {
    const int src = (tx < 16) ? (b * 16 + tx) : (2880 + b * 16 + tx - 16);
#pragma unroll
    for (int r = ty; r < 32; r += 8)
      tile[r][tx] = W[(size_t)(k0 + r) * 5760 + src];
  }
  __syncthreads();
#pragma unroll
  for (int o = ty; o < 32; o += 8)
    WT[(size_t)(b * 32 + o) * 1152 + k0 + tx] =
        (b < 180) ? (bf16_t)tile[tx][o] : (bf16_t)0.0f;
}

__global__ __launch_bounds__(256) void ada_kernel(
    const float* __restrict__ t_emb, const float* __restrict__ w_ada,
    const float* __restrict__ b_ada, const float* __restrict__ sst,
    float* __restrict__ ada)
{
  __shared__ float st[4][1152];
  const int t = threadIdx.x;
  const int j = blockIdx.x * 256 + t;
  for (int i = t; i < 4 * 1152; i += 256) {
    const int b = i / 1152, cc = i % 1152;
    const float v = t_emb[b * 1152 + cc];
    st[b][cc] = v / (1.0f + __expf(-v));
  }
  __syncthreads();
  const int k0 = blockIdx.y * 144;
  float a0 = 0.f, a1 = 0.f, a2 = 0.f, a3 = 0.f;
  for (int k = k0; k < k0 + 144; ++k) {
    const float w = w_ada[(size_t)k * 6912 + j];
    a0 += st[0][k] * w; a1 += st[1][k] * w;
    a2 += st[2][k] * w; a3 += st[3][k] * w;
  }
  if (blockIdx.y == 0) {
    const float base = b_ada[j] + sst[j];
    a0 += base; a1 += base; a2 += base; a3 += base;
  }
  atomicAdd(&ada[0 * 6912 + j], a0);
  atomicAdd(&ada[1 * 6912 + j], a1);
  atomicAdd(&ada[2 * 6912 + j], a2);
  atomicAdd(&ada[3 * 6912 + j], a3);
}

__global__ __launch_bounds__(256) void ln_mod(
    const float* __restrict__ X, bf16_t* __restrict__ out,
    const float* __restrict__ adaB, int shiftIdx, int scaleIdx,
    const float* __restrict__ gamma, const float* __restrict__ beta)
{
  const int row = blockIdx.x;
  const float4* xr4 = (const float4*)(X + (size_t)row * 1152);
  float s = 0.f, s2 = 0.f;
  for (int i = threadIdx.x; i < 288; i += 256) {
    const float4 v = xr4[i];
    s += v.x + v.y + v.z + v.w;
    s2 += v.x * v.x + v.y * v.y + v.z * v.z + v.w * v.w;
  }
  const int lane = threadIdx.x & 63, wave = threadIdx.x >> 6;
#pragma unroll
  for (int o = 32; o; o >>= 1) { s += __shfl_down(s, o); s2 += __shfl_down(s2, o); }
  __shared__ float rs[4], rq[4];
  if (lane == 0) { rs[wave] = s; rq[wave] = s2; }
  __syncthreads();
  if (threadIdx.x == 0) {
    rs[0] = rs[0] + rs[1] + rs[2] + rs[3];
    rq[0] = rq[0] + rq[1] + rq[2] + rq[3];
  }
  __syncthreads();
  const float mu = rs[0] * (1.0f / 1152.0f);
  const float var = rq[0] * (1.0f / 1152.0f) - mu * mu;
  const float inv = rsqrtf(var + 1e-6f);
  const int b = row >> 12;
  const float4* shiftv = (const float4*)(adaB ? adaB + b * 6912 + shiftIdx * 1152 : beta);
  const float4* scalev = (const float4*)(adaB ? adaB + b * 6912 + scaleIdx * 1152 : gamma);
  const float add1 = adaB ? 1.0f : 0.0f;
  for (int i = threadIdx.x; i < 288; i += 256) {
    const float4 v = xr4[i];
    const float4 sc = scalev[i];
    const float4 sh = shiftv[i];
    bf16x4 o;
    o[0] = (bf16_t)((v.x - mu) * inv * (add1 + sc.x) + sh.x);
    o[1] = (bf16_t)((v.y - mu) * inv * (add1 + sc.y) + sh.y);
    o[2] = (bf16_t)((v.z - mu) * inv * (add1 + sc.z) + sh.z);
    o[3] = (bf16_t)((v.w - mu) * inv * (add1 + sc.w) + sh.w);
    *(bf16x4*)&out[(size_t)row * 1152 + i * 4] = o;
  }
}

__global__ void pad_cond_k(const float* __restrict__ cond, bf16_t* __restrict__ condp)
{
  const int idx = blockIdx.x * 256 + threadIdx.x;
  const int row = idx / 1152;
  condp[idx] = (row < 1200) ? (bf16_t)cond[idx] : (bf16_t)0.0f;
}

__global__ __launch_bounds__(256) void sa_kv_k(
    const bf16_t* __restrict__ qkv, float* __restrict__ kvb, float* __restrict__ ksumb)
{
  const int bh = blockIdx.x, b = bh / 36, h = bh % 36;
  __shared__ bf16_t sk[32][32], sv[32][32];
  const int t = threadIdx.x;
  const int nn = t >> 5, c = t & 31;
  const int srow = (t & 127) >> 2;
  const int sq4 = (t & 3) * 8;
  const int isV = t >> 7;
  float a0 = 0.f, a1 = 0.f, a2 = 0.f, a3 = 0.f, ks = 0.f;
  const size_t rowbase = (size_t)b * 4096 + (size_t)blockIdx.y * 256;
  const size_t colbase = 1152 + (size_t)isV * 1152 + h * 32 + sq4;
  for (int n0 = 0; n0 < 256; n0 += 32) {
    __syncthreads();
    const bf16x8 v8 = *(const bf16x8*)&qkv[(rowbase + n0 + srow) * 3456 + colbase];
    if (isV == 0) {
      bf16x8 r8;
#pragma unroll
      for (int j = 0; j < 8; ++j) r8[j] = (bf16_t)fmaxf((float)v8[j], 0.0f);
      *(bf16x8*)&sk[srow][sq4] = r8;
    } else {
      *(bf16x8*)&sv[srow][sq4] = v8;
    }
    __syncthreads();
#pragma unroll
    for (int q = 0; q < 32; ++q) {
      const float vv = (float)sv[q][c];
      a0 += (float)sk[q][nn] * vv;
      a1 += (float)sk[q][nn + 8] * vv;
      a2 += (float)sk[q][nn + 16] * vv;
      a3 += (float)sk[q][nn + 24] * vv;
    }
    if (t < 32) {
#pragma unroll
      for (int q = 0; q < 32; ++q) ks += (float)sk[q][t];
    }
  }
  float* kvp = kvb + (size_t)bh * 1024;
  atomicAdd(&kvp[(nn + 0) * 32 + c], a0);
  atomicAdd(&kvp[(nn + 8) * 32 + c], a1);
  atomicAdd(&kvp[(nn + 16) * 32 + c], a2);
  atomicAdd(&kvp[(nn + 24) * 32 + c], a3);
  if (t < 32) atomicAdd(&ksumb[bh * 32 + t], ks);
}

__global__ __launch_bounds__(256) void sa_out_k(
    const bf16_t* __restrict__ qkv, const float* __restrict__ kvb,
    const float* __restrict__ ksumb, bf16_t* __restrict__ so)
{
  const int row0 = blockIdx.x * 8;
  const int b = row0 >> 12;
  __shared__ float q[8][1152];
  __shared__ float denom[8][36];
  const int t = threadIdx.x;
  for (int i = t; i < 1152; i += 256) {
    const int r = i / 144, c0 = (i % 144) * 8;
    const bf16x8 v8 = *(const bf16x8*)&qkv[(size_t)(row0 + r) * 3456 + c0];
#pragma unroll
    for (int j = 0; j < 8; ++j) q[r][c0 + j] = fmaxf((float)v8[j], 0.0f);
  }
  __syncthreads();
  for (int i = t; i < 288; i += 256) {
    int r = i / 36, h = i % 36;
    const float* ksp = ksumb + (b * 36 + h) * 32;
    float dsum = 1e-6f;
#pragma unroll
    for (int d = 0; d < 32; ++d) dsum += q[r][h * 32 + d] * ksp[d];
    denom[r][h] = dsum;
  }
  __syncthreads();
  for (int j = t; j < 1152; j += 256) {
    const int h = j >> 5, e = j & 31;
    const float* kvp = kvb + ((size_t)(b * 36 + h)) * 1024 + e;
    float kreg[32];
#pragma unroll
    for (int d = 0; d < 32; ++d) kreg[d] = kvp[d * 32];
#pragma unroll
    for (int r = 0; r < 8; ++r) {
      float a = 0.f;
#pragma unroll
      for (int d = 0; d < 32; ++d) a += q[r][h * 32 + d] * kreg[d];
      so[(size_t)(row0 + r) * 1152 + j] = (bf16_t)(a / denom[r][h]);
    }
  }
}

__global__ void ca_qrepack(const bf16_t* __restrict__ qc, bf16_t* __restrict__ qcp, int b)
{
  const size_t idx = (size_t)blockIdx.x * 256 + threadIdx.x;
  const int d = (int)(idx % 96);
  const size_t r = idx / 96;
  const int n = (int)(r & 4095);
  const int h = (int)(r >> 12);
  float v = 0.f;
  if (d < 72) v = (float)qc[((size_t)(b * 4096 + n)) * 1152 + h * 72 + d] * 0.11785113019775793f;
  qcp[idx] = (bf16_t)v;
}

__global__ void ca_kcrepack(const bf16_t* __restrict__ kvc, bf16_t* __restrict__ kcp, int b)
{
  const size_t idx = (size_t)blockIdx.x * 256 + threadIdx.x;
  const int d = (int)(idx % 96);
  const size_t r = idx / 96;
  const int m = (int)(r % 384);
  const int h = (int)(r / 384);
  bf16_t v = (bf16_t)0.0f;
  if (d < 72 && m < 300) v = kvc[((size_t)(b * 300 + m)) * 2304 + h * 72 + d];
  kcp[idx] = v;
}

__global__ void ca_vtrepack(const bf16_t* __restrict__ kvc, bf16_t* __restrict__ vt, int b)
{
  const size_t idx = (size_t)blockIdx.x * 256 + threadIdx.x;
  const int m = (int)(idx % 384);
  const size_t r = idx / 384;
  const int d = (int)(r & 127);
  const int h = (int)(r >> 7);
  bf16_t v = (bf16_t)0.0f;
  if (d < 72 && m < 300) v = kvc[((size_t)(b * 300 + m)) * 2304 + 1152 + h * 72 + d];
  vt[idx] = v;
}

__global__ __launch_bounds__(256) void softmax_k(bf16_t* __restrict__ s)
{
  const int row = blockIdx.x * 4 + (threadIdx.x >> 6);
  const int lane = threadIdx.x & 63;
  bf16_t* sr = s + (size_t)row * 384;
  float v[5];
  float mx = -1e30f;
#pragma unroll
  for (int i = 0; i < 5; ++i) {
    const int m = lane + 64 * i;
    v[i] = (m < 300) ? (float)sr[m] : -1e30f;
    mx = fmaxf(mx, v[i]);
  }
#pragma unroll
  for (int o = 32; o; o >>= 1) mx = fmaxf(mx, __shfl_xor(mx, o));
  float sum = 0.f;
#pragma unroll
  for (int i = 0; i < 5; ++i) { v[i] = __expf(v[i] - mx); sum += v[i]; }
#pragma unroll
  for (int o = 32; o; o >>= 1) sum += __shfl_xor(sum, o);
  const float inv = 1.0f / sum;
#pragma unroll
  for (int i = 0; i < 5; ++i) {
    const int m = lane + 64 * i;
    if (m < 320) sr[m] = (bf16_t)(v[i] * inv);
  }
}

__global__ __launch_bounds__(256) void dwconv_k(
    const bf16_t* __restrict__ h, const float* __restrict__ wk,
    const float* __restrict__ wb, bf16_t* __restrict__ hc)
{
  const size_t idx = (size_t)blockIdx.x * 256 + threadIdx.x;
  const int c8 = (int)(idx % 360);
  size_t p = idx / 360;
  const int x = (int)(p & 63);
  const int y = (int)(p >> 6);
  const int c0 = c8 * 8;
  float acc[8];
#pragma unroll
  for (int j = 0; j < 8; ++j) acc[j] = wb[c0 + j];
  for (int ky = -1; ky <= 1; ++ky) {
    const int yy = y + ky;
    if (yy < 0 || yy > 63) continue;
    for (int kx = -1; kx <= 1; ++kx) {
      const int xx = x + kx;
      if (xx < 0 || xx > 63) continue;
      const bf16x8 v = *(const bf16x8*)&h[((size_t)(yy * 64 + xx)) * 2880 + c0];
      const float* w = wk + ((ky + 1) * 3 + (kx + 1)) * 2880 + c0;
#pragma unroll
      for (int j = 0; j < 8; ++j) acc[j] += (float)v[j] * w[j];
    }
  }
  bf16x8 o;
#pragma unroll
  for (int j = 0; j < 8; ++j) o[j] = (bf16_t)acc[j];
  *(bf16x8*)&hc[((size_t)(y * 64 + x)) * 2880 + c0] = o;
}

// ---------------------------------------------------------------------------
extern "C" void kernel_launch(void* const* d_in, const int* in_sizes, int n_in,
                              void* d_out, int out_size, void* d_ws, size_t ws_size,
                              hipStream_t stream)
{
  const float* x          = (const float*)d_in[0];
  const float* cond       = (const float*)d_in[1];
  const float* t_emb      = (const float*)d_in[2];
  const float* w_qkv      = (const float*)d_in[3];
  const float* w_sa_out   = (const float*)d_in[4];
  const float* b_sa_out   = (const float*)d_in[5];
  const float* gamma_cr   = (const float*)d_in[6];
  const float* beta_cr    = (const float*)d_in[7];
  const float* w_q        = (const float*)d_in[8];
  const float* b_q        = (const float*)d_in[9];
  const float* w_kv       = (const float*)d_in[10];
  const float* b_kv       = (const float*)d_in[11];
  const float* w_co       = (const float*)d_in[12];
  const float* b_co       = (const float*)d_in[13];
  const float* w_fc1      = (const float*)d_in[14];
  const float* b_fc1      = (const float*)d_in[15];
  const float* dw_kernel  = (const float*)d_in[16];
  const float* dw_bias    = (const float*)d_in[17];
  const float* w_fc2      = (const float*)d_in[18];
  const float* b_fc2      = (const float*)d_in[19];
  const float* w_ada      = (const float*)d_in[20];
  const float* b_ada      = (const float*)d_in[21];
  const float* sst        = (const float*)d_in[22];
  float* out = (float*)d_out;  // f32 residual stream

  char* ws = (char*)d_ws;
  size_t off = 0;
  auto alloc = [&](size_t bytes) -> char* {
    off = (off + 255) & ~(size_t)255;
    char* p = ws + off;
    off += bytes;
    return p;
  };

  bf16_t* wqkvT  = (bf16_t*)alloc((size_t)3584 * 1152 * 2);
  bf16_t* wsaT   = (bf16_t*)alloc((size_t)1280 * 1152 * 2);
  bf16_t* wqT    = (bf16_t*)alloc((size_t)1280 * 1152 * 2);
  bf16_t* wkvT   = (bf16_t*)alloc((size_t)2304 * 1152 * 2);
  bf16_t* wcoT   = (bf16_t*)alloc((size_t)1280 * 1152 * 2);
  bf16_t* wfc1P  = (bf16_t*)alloc((size_t)5888 * 1152 * 2);  // GLU-permuted
  bf16_t* wfc2T  = (bf16_t*)alloc((size_t)1280 * 2880 * 2);
  float*  adaB   = (float*)alloc((size_t)4 * 6912 * 4);
  bf16_t* xn     = (bf16_t*)alloc((size_t)16384 * 1152 * 2);
  bf16_t* buf37  = (bf16_t*)alloc((size_t)16384 * 1152 * 2);
  float*  kvb    = (float*)alloc((size_t)144 * 1024 * 4);
  float*  ksumb  = (float*)alloc((size_t)144 * 32 * 4);
  bf16_t* condp  = (bf16_t*)alloc((size_t)1280 * 1152 * 2);
  bf16_t* kvcB   = (bf16_t*)alloc((size_t)1280 * 2304 * 2);

  const size_t ARENA_SMALL = (size_t)16384 * 3456 * 2;
  const size_t CA_Q = (size_t)64 * 4096 * 96 * 2;
  const size_t CA_K = (size_t)64 * 384 * 96 * 2;
  const size_t CA_V = (size_t)64 * 128 * 384 * 2;
  const size_t CA_S = (size_t)64 * 4096 * 384 * 2;
  const size_t ARENA_BIG = CA_Q + CA_K + CA_V + CA_S;
  const bool big = (off + 512 + ARENA_BIG) <= ws_size;
  char* arena = alloc(big ? ARENA_BIG : ARENA_SMALL);
  if (off > ws_size) return;

  bf16_t* qkvB = (bf16_t*)arena;
  bf16_t *qcp, *kcp, *vcT, *scores;
  if (big) {
    qcp    = (bf16_t*)arena;
    kcp    = (bf16_t*)(arena + CA_Q);
    vcT    = (bf16_t*)(arena + CA_Q + CA_K);
    scores = (bf16_t*)(arena + CA_Q + CA_K + CA_V);
  } else {
    qcp    = (bf16_t*)arena;
    kcp    = (bf16_t*)(arena + 12582912);
    vcT    = (bf16_t*)(arena + 12582912 + 1179648);
    scores = (bf16_t*)(arena + 12582912 + 1179648 + 1572864);
  }
  bf16_t *hB, *hcB;
  if (big) {   // h(2b) 47.2 | hc(4b) 94.4  (gv eliminated by GLU fusion)
    hB  = (bf16_t*)arena;
    hcB = (bf16_t*)(arena + (size_t)8192 * 2880 * 2);
  } else {     // h(1b) in buf37; hc(2b) at arena
    hcB = (bf16_t*)arena;
    hB  = buf37;
  }

  hipMemsetAsync(adaB, 0, (size_t)4 * 6912 * 4, stream);
  hipMemsetAsync(kvb, 0, (size_t)144 * 1024 * 4, stream);
  hipMemsetAsync(ksumb, 0, (size_t)144 * 32 * 4, stream);

  // --- weight prep ---
  transpose_cast<<<dim3(108, 36), 256, 0, stream>>>(w_qkv, wqkvT, 1152, 3456);
  transpose_cast<<<dim3(36, 36), 256, 0, stream>>>(w_sa_out, wsaT, 1152, 1152);
  transpose_cast<<<dim3(36, 36), 256, 0, stream>>>(w_q, wqT, 1152, 1152);
  transpose_cast<<<dim3(72, 36), 256, 0, stream>>>(w_kv, wkvT, 1152, 2304);
  transpose_cast<<<dim3(36, 36), 256, 0, stream>>>(w_co, wcoT, 1152, 1152);
  transpose_glu<<<dim3(184, 36), 256, 0, stream>>>(w_fc1, wfc1P);
  transpose_cast<<<dim3(36, 90), 256, 0, stream>>>(w_fc2, wfc2T, 2880, 1152);
  ada_kernel<<<dim3(27, 8), 256, 0, stream>>>(t_emb, w_ada, b_ada, sst, adaB);
  pad_cond_k<<<5760, 256, 0, stream>>>(cond, condp);

  // --- self (linear) attention ---
  ln_mod<<<16384, 256, 0, stream>>>(x, xn, adaB, 0, 1, nullptr, nullptr);
  gemm256r<0><<<dim3(14, 64), 512, 0, stream>>>(xn, wqkvT, qkvB, 16384, 3456, 1152,
                                                nullptr, nullptr, nullptr, 8);
  sa_kv_k<<<dim3(144, 16), 256, 0, stream>>>(qkvB, kvb, ksumb);
  sa_out_k<<<2048, 256, 0, stream>>>(qkvB, kvb, ksumb, buf37);
  gemm_bt<1><<<dim3(9, 128), 256, 0, stream>>>(buf37, wsaT, out, 16384, 1152, 1152,
                                               0, 0, 0, b_sa_out, x, adaB + 2 * 1152, 8);

  // --- cross attention ---
  ln_mod<<<16384, 256, 0, stream>>>(out, xn, nullptr, 0, 0, gamma_cr, beta_cr);
  gemm_bt<0><<<dim3(18, 10, 1), 256, 0, stream>>>(condp, wkvT, kvcB, 1280, 2304, 1152,
                                                  0, 0, 0, b_kv, nullptr, nullptr, 8);
  if (big) {
    hipMemsetAsync(qcp, 0, CA_Q, stream);          // zero d-padding (after SA)
    gemm_bt<3><<<dim3(9, 128), 256, 0, stream>>>(xn, wqT, qcp, 16384, 1152, 1152,
                                                 0, 0, 0, b_q, nullptr, nullptr, 8);
    for (int b = 0; b < 4; ++b) {
      ca_kcrepack<<<2304, 256, 0, stream>>>(kvcB, kcp + (size_t)b * 16 * 384 * 96, b);
      ca_vtrepack<<<3072, 256, 0, stream>>>(kvcB, vcT + (size_t)b * 16 * 128 * 384, b);
    }
    gemm_bt<0><<<dim3(3, 32, 64), 256, 0, stream>>>(qcp, kcp, scores, 4096, 384, 96,
                                                    (long)4096 * 96, (long)384 * 96,
                                                    (long)4096 * 384, nullptr, nullptr, nullptr, 8);
    softmax_k<<<65536, 256, 0, stream>>>(scores);
    gemm_bt<2><<<dim3(1, 32, 64), 256, 0, stream>>>(scores, vcT, buf37, 4096, 128, 384,
                                                    (long)4096 * 384, (long)128 * 384,
                                                    0, nullptr, nullptr, nullptr, 8);
  } else {
    gemm_bt<0><<<dim3(9, 128), 256, 0, stream>>>(xn, wqT, buf37, 16384, 1152, 1152,
                                                 0, 0, 0, b_q, nullptr, nullptr, 8);
    for (int b = 0; b < 4; ++b) {
      ca_qrepack<<<24576, 256, 0, stream>>>(buf37, qcp, b);
      ca_kcrepack<<<2304, 256, 0, stream>>>(kvcB, kcp, b);
      ca_vtrepack<<<3072, 256, 0, stream>>>(kvcB, vcT, b);
      gemm_bt<0><<<dim3(3, 32, 16), 256, 0, stream>>>(qcp, kcp, scores, 4096, 384, 96,
                                                      (long)4096 * 96, (long)384 * 96,
                                                      (long)4096 * 384, nullptr, nullptr, nullptr, 8);
      softmax_k<<<16384, 256, 0, stream>>>(scores);
      gemm_bt<2><<<dim3(1, 32, 16), 256, 0, stream>>>(scores, vcT,
                                                      buf37 + (size_t)b * 4096 * 1152,
                                                      4096, 128, 384,
                                                      (long)4096 * 384, (long)128 * 384,
                                                      0, nullptr, nullptr, nullptr, 8);
    }
  }
  gemm_bt<1><<<dim3(9, 128), 256, 0, stream>>>(buf37, wcoT, out, 16384, 1152, 1152,
                                               0, 0, 0, b_co, out, nullptr, 8);

  // --- FF (fc1+GLU fused, depthwise conv, fc2) ---
  ln_mod<<<16384, 256, 0, stream>>>(out, xn, adaB, 3, 4, nullptr, nullptr);
  if (big) {
    for (int c = 0; c < 2; ++c) {
      gemm256r<4><<<dim3(23, 32), 512, 0, stream>>>(xn + (size_t)c * 8192 * 1152, wfc1P,
                                                    hB, 8192, 5760, 1152,
                                                    b_fc1, nullptr, nullptr, 8);
      for (int bb = 0; bb < 2; ++bb)
        dwconv_k<<<5760, 256, 0, stream>>>(hB + (size_t)bb * 4096 * 2880,
                                           dw_kernel, dw_bias,
                                           hcB + (size_t)(c * 2 + bb) * 4096 * 2880);
    }
    gemm_bt<1><<<dim3(9, 128), 256, 0, stream>>>(hcB, wfc2T, out, 16384, 1152, 2880,
                                                 0, 0, 0, b_fc2, out,
                                                 adaB + 5 * 1152, 8);
  } else {
    for (int c = 0; c < 2; ++c) {
      for (int bb = 0; bb < 2; ++bb) {
        const int b = c * 2 + bb;
        gemm256r<4><<<dim3(23, 16), 512, 0, stream>>>(xn + (size_t)b * 4096 * 1152, wfc1P,
                                                      hB, 4096, 5760, 1152,
                                                      b_fc1, nullptr, nullptr, 8);
        dwconv_k<<<5760, 256, 0, stream>>>(hB, dw_kernel, dw_bias,
                                           hcB + (size_t)bb * 4096 * 2880);
      }
      gemm_bt<1><<<dim3(9, 64), 256, 0, stream>>>(hcB, wfc2T,
                                                  out + (size_t)c * 8192 * 1152,
                                                  8192, 1152, 2880, 0, 0, 0, b_fc2,
                                                  out + (size_t)c * 8192 * 1152,
                                                  adaB + (size_t)c * 2 * 6912 + 5 * 1152, 8);
    }
  }

  (void)in_sizes; (void)n_in; (void)out_size; (void)ws_size;
}